// Round 2
// 5640.067 us; speedup vs baseline: 1.2672x; 1.2672x over previous
//
#include <hip/hip_runtime.h>

typedef __bf16 bf16x8 __attribute__((ext_vector_type(8)));
typedef float f32x4 __attribute__((ext_vector_type(4)));

#define DIMH 1024
#define SEQL 1024
#define BATCHN 4
#define NROWS (BATCHN*SEQL)   // 4096

// ============================ embedding gather ============================
__global__ __launch_bounds__(256) void embed_kernel(const int* __restrict__ x,
        const float* __restrict__ emb, float* __restrict__ h) {
  int row = blockIdx.x;                       // 0..4095 = b*L + l
  int tok = x[row];
  const f32x4* src = (const f32x4*)(emb + (size_t)tok*DIMH);
  f32x4* dst = (f32x4*)(h + (size_t)row*DIMH);
  dst[threadIdx.x] = src[threadIdx.x];
}

// ============================ layernorm ============================
__global__ __launch_bounds__(256) void ln_kernel(const float* __restrict__ x,
        const float* __restrict__ w, const float* __restrict__ b,
        float* __restrict__ outf, __bf16* __restrict__ outb) {
  int row = blockIdx.x;
  int tid = threadIdx.x;
  const f32x4* xr = (const f32x4*)(x + (size_t)row*DIMH);
  f32x4 v = xr[tid];
  float s  = v.x+v.y+v.z+v.w;
  float ss = v.x*v.x+v.y*v.y+v.z*v.z+v.w*v.w;
  for (int off=32; off; off>>=1) { s += __shfl_xor(s,off); ss += __shfl_xor(ss,off); }
  __shared__ float sb[8];
  int wave = tid>>6, lane = tid&63;
  if (lane==0){ sb[wave]=s; sb[4+wave]=ss; }
  __syncthreads();
  s  = sb[0]+sb[1]+sb[2]+sb[3];
  ss = sb[4]+sb[5]+sb[6]+sb[7];
  float mean = s*(1.0f/DIMH);
  float var  = ss*(1.0f/DIMH) - mean*mean;
  float rstd = rsqrtf(var + 1e-5f);
  const f32x4* wv = (const f32x4*)w; const f32x4* bv = (const f32x4*)b;
  f32x4 wl = wv[tid], bl = bv[tid];
  f32x4 o;
  o.x = (v.x-mean)*rstd*wl.x + bl.x;
  o.y = (v.y-mean)*rstd*wl.y + bl.y;
  o.z = (v.z-mean)*rstd*wl.z + bl.z;
  o.w = (v.w-mean)*rstd*wl.w + bl.w;
  if (outf) ((f32x4*)(outf + (size_t)row*DIMH))[tid] = o;
  if (outb) {
    __bf16* ob = outb + (size_t)row*DIMH + tid*4;
    ob[0]=(__bf16)o.x; ob[1]=(__bf16)o.y; ob[2]=(__bf16)o.z; ob[3]=(__bf16)o.w;
  }
}

// ============================ S4D diagonal scan ============================
__global__ __launch_bounds__(256) void s4_scan_kernel(
    const float* __restrict__ u, const float* __restrict__ log_dt,
    const float* __restrict__ A_re, const float* __restrict__ A_im,
    const float* __restrict__ C_re, const float* __restrict__ C_im,
    const float* __restrict__ Dp, __bf16* __restrict__ yout) {
  int b = blockIdx.x >> 7;
  int hblk = blockIdx.x & 127;
  int tid = threadIdx.x;
  int ch = tid >> 5;          // 0..7
  int n  = tid & 31;          // state index
  int h = hblk*8 + ch;
  int hn = h*32 + n;
  float dt  = __expf(log_dt[h]);
  float Are = A_re[hn], Aim = A_im[hn];
  float ar = dt*Are, ai = dt*Aim;
  float er = __expf(ar);
  float sn_, cs_; __sincosf(ai, &sn_, &cs_);
  float lr = er*cs_, li = er*sn_;            // lambda = exp(dtA)
  float wr = lr - 1.0f, wi = li;             // lambda - 1
  float inv = 1.0f/(Are*Are + Aim*Aim);
  float qr = (wr*Are + wi*Aim)*inv;          // (lambda-1)/A
  float qi = (wi*Are - wr*Aim)*inv;
  float Cr = C_re[hn], Ci = C_im[hn];
  float dcr = Cr*qr - Ci*qi;                 // dC = C*(lambda-1)/A
  float dci = Cr*qi + Ci*qr;
  float Dv = Dp[h];
  __shared__ float u_s[64][8];
  __shared__ float y_s[64][8];
  const float* ubase = u + ((size_t)b*SEQL)*DIMH + hblk*8;
  __bf16* ybase = yout + ((size_t)b*SEQL)*DIMH + hblk*8;
  float sr = 0.f, si = 0.f;
  for (int l0=0; l0<SEQL; l0+=64) {
    __syncthreads();
    for (int t=tid; t<512; t+=256) {
      int lt = t>>3, c = t&7;
      u_s[lt][c] = ubase[(size_t)(l0+lt)*DIMH + c];
    }
    __syncthreads();
    for (int lt=0; lt<64; ++lt) {
      float uv = u_s[lt][ch];
      float nsr = fmaf(lr, sr, fmaf(-li, si, uv));
      float nsi = fmaf(lr, si, li*sr);
      sr = nsr; si = nsi;
      float contrib = dcr*sr - dci*si;       // Re(dC * s)
      contrib += __shfl_xor(contrib, 16);
      contrib += __shfl_xor(contrib, 8);
      contrib += __shfl_xor(contrib, 4);
      contrib += __shfl_xor(contrib, 2);
      contrib += __shfl_xor(contrib, 1);
      if (n==0) {
        float yv = 2.0f*contrib + uv*Dv;
        float t2 = 0.7978845608028654f*(yv + 0.044715f*yv*yv*yv);
        t2 = fminf(t2, 15.0f);
        float e = __expf(2.0f*t2);
        float th = (e-1.0f)/(e+1.0f);
        y_s[lt][ch] = 0.5f*yv*(1.0f+th);
      }
    }
    __syncthreads();
    for (int t=tid; t<512; t+=256) {
      int lt=t>>3, c=t&7;
      ybase[(size_t)(l0+lt)*DIMH + c] = (__bf16)y_s[lt][c];
    }
  }
}

// ============================ LDS-staged GEMM ============================
// C = act(A @ W^T + bias).  A: bf16 [4096, K]; W: f32 [N_w, K] (converted to
// bf16 tile-wise into LDS).  128x128 tile, BK=32, double-buffered.
// A staged via global_load_lds width-16 (linear [128][32] bf16 layout);
// W staged reg->cvt->ds_write_b128 (one conversion per tile, not per k-step).
// Grid: (M/128, Nout/128) with M FASTEST so consecutive blocks share a W tile
// (L2-resident W reuse; the old N-fast order over-fetched W ~18x).
// ACT: 0 = none (+bias,+resid), 1 = GLU sigmoid, 2 = GLU silu.

__device__ __forceinline__ void gload_lds16(const void* g, void* l) {
  __builtin_amdgcn_global_load_lds(
      (const __attribute__((address_space(1))) void*)g,
      (__attribute__((address_space(3))) void*)l, 16, 0, 0);
}

template<int ACT>
__global__ __launch_bounds__(256) void gemm_kernel(
    const __bf16* __restrict__ A, const float* __restrict__ W,
    const float* __restrict__ bias, const float* __restrict__ resid,
    float* __restrict__ outf, __bf16* __restrict__ outb,
    int Nout, int K) {
  constexpr int TILE = 128*32;                       // elems per buffer
  __shared__ __align__(16) __bf16 smem[(ACT ? 6 : 4) * TILE];
  __bf16* As = smem;                                  // [2][TILE]
  __bf16* Wa = smem + 2*TILE;                         // [2][TILE]
  __bf16* Wg = ACT ? (smem + 4*TILE) : nullptr;       // [2][TILE] (GLU g-half)

  int tid = threadIdx.x;
  int wave = tid>>6, lane = tid&63;
  int quad = lane>>4, l16 = lane&15;
  int m0 = blockIdx.x*128;
  int n0 = blockIdx.y*128;
  int wm = wave>>1, wn = wave&1;                      // 2x2 waves -> 64x64 each

  f32x4 acc[4][4];
  f32x4 accg[4][4];
  f32x4 zero = {0.f,0.f,0.f,0.f};
#pragma unroll
  for (int i=0;i<4;i++)
#pragma unroll
    for (int j=0;j<4;j++){ acc[i][j]=zero; if (ACT) accg[i][j]=zero; }

  size_t goff = (size_t)Nout*K;

  auto stage = [&](int buf, int k0) {
    // --- W f32 loads first (older in vmcnt order than the A gload_lds) ---
    f32x4 wlo[2], whi[2], glo[2], ghi[2];
#pragma unroll
    for (int c=0;c<2;c++) {
      int idx = c*256 + tid;                 // 0..511
      int rr = idx>>2, kq = (idx&3)*8;       // row 0..127, k 0/8/16/24
      const float* p = W + (size_t)(n0+rr)*K + k0 + kq;
      wlo[c] = *(const f32x4*)p; whi[c] = *(const f32x4*)(p+4);
      if (ACT) {
        const float* pg = p + goff;
        glo[c] = *(const f32x4*)pg; ghi[c] = *(const f32x4*)(pg+4);
      }
    }
    // --- A: async global->LDS, 2 x 16B per lane per wave (linear layout) ---
#pragma unroll
    for (int q=0;q<2;q++) {
      int off = ((wave*2+q)*64 + lane)*16;   // byte offset into 8 KB tile
      int row = off>>6, kb = off&63;         // row-major [128][32] bf16
      const char* src = (const char*)A + ((size_t)(m0+row)*K + k0)*2 + kb;
      char* dst = (char*)As + (size_t)buf*TILE*2 + (size_t)(wave*2+q)*1024;
      gload_lds16(src, dst);
    }
    // --- W: cvt + ds_write_b128 ---
#pragma unroll
    for (int c=0;c<2;c++) {
      int idx = c*256 + tid;
      int rr = idx>>2, kq = (idx&3)*8;
      bf16x8 t;
      t[0]=(__bf16)wlo[c].x; t[1]=(__bf16)wlo[c].y; t[2]=(__bf16)wlo[c].z; t[3]=(__bf16)wlo[c].w;
      t[4]=(__bf16)whi[c].x; t[5]=(__bf16)whi[c].y; t[6]=(__bf16)whi[c].z; t[7]=(__bf16)whi[c].w;
      *(bf16x8*)(Wa + buf*TILE + rr*32 + kq) = t;
      if (ACT) {
        bf16x8 t2;
        t2[0]=(__bf16)glo[c].x; t2[1]=(__bf16)glo[c].y; t2[2]=(__bf16)glo[c].z; t2[3]=(__bf16)glo[c].w;
        t2[4]=(__bf16)ghi[c].x; t2[5]=(__bf16)ghi[c].y; t2[6]=(__bf16)ghi[c].z; t2[7]=(__bf16)ghi[c].w;
        *(bf16x8*)(Wg + buf*TILE + rr*32 + kq) = t2;
      }
    }
  };

  stage(0, 0);
  __syncthreads();                            // drains vmcnt+lgkmcnt, barrier

  int nt = K/32;
  for (int t=0; t<nt; ++t) {
    int cur = t&1, nxt = cur^1;
    if (t+1 < nt) stage(nxt, (t+1)*32);       // prefetch next tile
    int base = cur*TILE;
    bf16x8 af[4], wf[4], wgf[4];
#pragma unroll
    for (int i=0;i<4;i++)
      af[i] = *(const bf16x8*)(As + base + (wm*64 + i*16 + l16)*32 + quad*8);
#pragma unroll
    for (int j=0;j<4;j++) {
      wf[j] = *(const bf16x8*)(Wa + base + (wn*64 + j*16 + l16)*32 + quad*8);
      if (ACT) wgf[j] = *(const bf16x8*)(Wg + base + (wn*64 + j*16 + l16)*32 + quad*8);
    }
#pragma unroll
    for (int i=0;i<4;i++)
#pragma unroll
      for (int j=0;j<4;j++) {
        acc[i][j] = __builtin_amdgcn_mfma_f32_16x16x32_bf16(af[i], wf[j], acc[i][j], 0,0,0);
        if (ACT)
          accg[i][j] = __builtin_amdgcn_mfma_f32_16x16x32_bf16(af[i], wgf[j], accg[i][j], 0,0,0);
      }
    __syncthreads();                          // next tile staged + reads done
  }

  // epilogue — C/D layout: col = lane&15, row = quad*4 + reg  [verified mapping]
#pragma unroll
  for (int i=0;i<4;i++) {
#pragma unroll
    for (int j=0;j<4;j++) {
      int colg = n0 + wn*64 + j*16 + l16;
      float ba = bias[colg];
      float bg = ACT ? bias[Nout + colg] : 0.f;
#pragma unroll
      for (int rr=0;rr<4;rr++) {
        int rowg = m0 + wm*64 + i*16 + quad*4 + rr;
        float v = acc[i][j][rr] + ba;
        if (ACT) {
          float g = accg[i][j][rr] + bg;
          float sg = 1.0f/(1.0f+__expf(-g));
          v = (ACT==1) ? v*sg : v*(g*sg);
        }
        size_t idx = (size_t)rowg*Nout + colg;
        if (resid) v += resid[idx];
        if (outf) outf[idx] = v;
        if (outb) outb[idx] = (__bf16)v;
      }
    }
  }
}

// ============================ host ============================
static void launch_gemm(int act, const __bf16* A, const float* W, const float* bias,
                        const float* resid, float* outf, __bf16* outb,
                        int Nout, int K, hipStream_t s) {
  dim3 g(NROWS/128, Nout/128), b(256);       // M fastest -> W-tile L2 reuse
  if (act==0)      gemm_kernel<0><<<g,b,0,s>>>(A,W,bias,resid,outf,outb,Nout,K);
  else if (act==1) gemm_kernel<1><<<g,b,0,s>>>(A,W,bias,resid,outf,outb,Nout,K);
  else             gemm_kernel<2><<<g,b,0,s>>>(A,W,bias,resid,outf,outb,Nout,K);
}

extern "C" void kernel_launch(void* const* d_in, const int* in_sizes, int n_in,
                              void* d_out, int out_size, void* d_ws, size_t ws_size,
                              hipStream_t stream) {
  (void)in_sizes; (void)n_in; (void)out_size; (void)ws_size;
  const int*   x        = (const int*)d_in[0];
  // d_in[1] = length (unused by reference)
  const float* emb      = (const float*)d_in[2];
  const float* s4_log_dt= (const float*)d_in[3];
  const float* s4_A_re  = (const float*)d_in[4];
  const float* s4_A_im  = (const float*)d_in[5];
  const float* s4_C_re  = (const float*)d_in[6];
  const float* s4_C_im  = (const float*)d_in[7];
  const float* s4_D     = (const float*)d_in[8];
  const float* s4_out_w = (const float*)d_in[9];
  const float* s4_out_b = (const float*)d_in[10];
  const float* norm1_w  = (const float*)d_in[11];
  const float* norm1_b  = (const float*)d_in[12];
  const float* norm2_w  = (const float*)d_in[13];
  const float* norm2_b  = (const float*)d_in[14];
  const float* ff_w1    = (const float*)d_in[15];
  const float* ff_b1    = (const float*)d_in[16];
  const float* ff_w2    = (const float*)d_in[17];
  const float* ff_b2    = (const float*)d_in[18];
  const float* post_w   = (const float*)d_in[19];
  const float* post_b   = (const float*)d_in[20];
  const float* out_w    = (const float*)d_in[21];
  const float* out_b    = (const float*)d_in[22];

  char* ws = (char*)d_ws;
  float*  h    = (float*)(ws + 0);                    // 16 MB  [4096,1024] f32
  float*  r    = (float*)(ws + (16u<<20));            // 16 MB  [4096,1024] f32
  __bf16* yb   = (__bf16*)(ws + (32u<<20));           //  8 MB  [4096,1024] bf16
  __bf16* lnb  = (__bf16*)(ws + (40u<<20));           //  8 MB  [4096,1024] bf16
  __bf16* glub = (__bf16*)(ws + (48u<<20));           // 32 MB  [4096,4096] bf16
  float*  logits = (float*)d_out;                     // [4096,32000] f32

  embed_kernel<<<NROWS,256,0,stream>>>(x, emb, h);

  for (int i=0;i<4;i++) {
    // ---- S4 block: r = LN1(h); r = S4(S4(r)); h = r + h ----
    ln_kernel<<<NROWS,256,0,stream>>>(h, norm1_w+(size_t)i*DIMH, norm1_b+(size_t)i*DIMH, r, lnb);
    for (int j=0;j<2;j++) {
      int k = 2*i+j;
      s4_scan_kernel<<<512,256,0,stream>>>(r, s4_log_dt + (size_t)k*DIMH,
          s4_A_re + (size_t)k*DIMH*32, s4_A_im + (size_t)k*DIMH*32,
          s4_C_re + (size_t)k*DIMH*32, s4_C_im + (size_t)k*DIMH*32,
          s4_D + (size_t)k*DIMH, yb);
      const float* sw    = s4_out_w + (size_t)k*2048*DIMH;
      const float* sbias = s4_out_b + (size_t)k*2048;
      if (j==0)  // r = a*sigmoid(g)
        launch_gemm(1, yb, sw, sbias, nullptr, r, nullptr, DIMH, DIMH, stream);
      else       // h = a*sigmoid(g) + h
        launch_gemm(1, yb, sw, sbias, h, h, nullptr, DIMH, DIMH, stream);
    }
    // ---- FFN block: r = LN2(h); h = (a*silu(g)) @ w2^T + b2 + h ----
    ln_kernel<<<NROWS,256,0,stream>>>(h, norm2_w+(size_t)i*DIMH, norm2_b+(size_t)i*DIMH, r, lnb);
    launch_gemm(2, lnb, ff_w1 + (size_t)i*8192*DIMH, ff_b1 + (size_t)i*8192,
                nullptr, nullptr, glub, 4096, DIMH, stream);
    launch_gemm(0, glub, ff_w2 + (size_t)i*DIMH*4096, ff_b2 + (size_t)i*DIMH,
                h, h, nullptr, DIMH, 4096, stream);
  }

  // ---- post-norm + logits ----
  ln_kernel<<<NROWS,256,0,stream>>>(h, post_w, post_b, r, lnb);
  launch_gemm(0, lnb, out_w, out_b, nullptr, logits, nullptr, 32000, DIMH, stream);
}

// Round 3
// 3977.938 us; speedup vs baseline: 1.7966x; 1.4178x over previous
//
#include <hip/hip_runtime.h>

typedef __bf16 bf16x8 __attribute__((ext_vector_type(8)));
typedef float f32x4 __attribute__((ext_vector_type(4)));

#define DIMH 1024
#define SEQL 1024
#define BATCHN 4
#define NROWS (BATCHN*SEQL)   // 4096
#define CHUNK 128
#define NCHUNK (SEQL/CHUNK)   // 8

// ============================ embedding gather ============================
__global__ __launch_bounds__(256) void embed_kernel(const int* __restrict__ x,
        const float* __restrict__ emb, float* __restrict__ h) {
  int row = blockIdx.x;                       // 0..4095 = b*L + l
  int tok = x[row];
  const f32x4* src = (const f32x4*)(emb + (size_t)tok*DIMH);
  f32x4* dst = (f32x4*)(h + (size_t)row*DIMH);
  dst[threadIdx.x] = src[threadIdx.x];
}

// ============================ layernorm ============================
__global__ __launch_bounds__(256) void ln_kernel(const float* __restrict__ x,
        const float* __restrict__ w, const float* __restrict__ b,
        float* __restrict__ outf, __bf16* __restrict__ outb) {
  int row = blockIdx.x;
  int tid = threadIdx.x;
  const f32x4* xr = (const f32x4*)(x + (size_t)row*DIMH);
  f32x4 v = xr[tid];
  float s  = v.x+v.y+v.z+v.w;
  float ss = v.x*v.x+v.y*v.y+v.z*v.z+v.w*v.w;
  for (int off=32; off; off>>=1) { s += __shfl_xor(s,off); ss += __shfl_xor(ss,off); }
  __shared__ float sb[8];
  int wave = tid>>6, lane = tid&63;
  if (lane==0){ sb[wave]=s; sb[4+wave]=ss; }
  __syncthreads();
  s  = sb[0]+sb[1]+sb[2]+sb[3];
  ss = sb[4]+sb[5]+sb[6]+sb[7];
  float mean = s*(1.0f/DIMH);
  float var  = ss*(1.0f/DIMH) - mean*mean;
  float rstd = rsqrtf(var + 1e-5f);
  const f32x4* wv = (const f32x4*)w; const f32x4* bv = (const f32x4*)b;
  f32x4 wl = wv[tid], bl = bv[tid];
  f32x4 o;
  o.x = (v.x-mean)*rstd*wl.x + bl.x;
  o.y = (v.y-mean)*rstd*wl.y + bl.y;
  o.z = (v.z-mean)*rstd*wl.z + bl.z;
  o.w = (v.w-mean)*rstd*wl.w + bl.w;
  if (outf) ((f32x4*)(outf + (size_t)row*DIMH))[tid] = o;
  if (outb) {
    __bf16* ob = outb + (size_t)row*DIMH + tid*4;
    ob[0]=(__bf16)o.x; ob[1]=(__bf16)o.y; ob[2]=(__bf16)o.z; ob[3]=(__bf16)o.w;
  }
}

// ============================ S4D chunked scan ============================
// Linear recurrence s[l] = lambda*s[l-1] + u[l] split into NCHUNK chunks of
// CHUNK steps. Pass 1: chunk-local scan from zero state -> partial y (f32,
// pre-GELU, incl. D*u) + chunk-end states. Pass 2: cross-chunk carry via
// Horner with lambda^CHUNK (direct exp/sincos), per-step correction
// 2*Re(dC * lambda^{t+1} * carry), GELU, bf16 out.
// Grid: B(4) x 64 h-groups(16ch) x NCHUNK(8) = 2048 one-wave blocks.
// Lane map: ch = lane>>2 (16 channels), slot = lane&3, 8 states per lane.

__global__ __launch_bounds__(64) void s4_chunk_kernel(
    const float* __restrict__ u, const float* __restrict__ log_dt,
    const float* __restrict__ A_re, const float* __restrict__ A_im,
    const float* __restrict__ C_re, const float* __restrict__ C_im,
    const float* __restrict__ Dp,
    float* __restrict__ ypart,        // [4096][1024] f32
    float* __restrict__ send) {       // [B][NCHUNK][1024][32] float2
  int bid = blockIdx.x;
  int k   = bid & (NCHUNK-1);
  int hgb = (bid >> 3) & 63;
  int b   = bid >> 9;
  int lane = threadIdx.x;
  int ch = lane >> 2, slot = lane & 3;
  int h = hgb*16 + ch;

  float dt = __expf(log_dt[h]);
  float Dv = Dp[h];
  float lr[8], li[8], dcr[8], dci[8], sr[8], si[8];
#pragma unroll
  for (int j=0;j<8;j++) {
    int hn = h*32 + slot*8 + j;
    float Are = A_re[hn], Aim = A_im[hn];
    float ar = dt*Are, ai = dt*Aim;
    float er = __expf(ar);
    float sn_, cs_; __sincosf(ai, &sn_, &cs_);
    lr[j] = er*cs_; li[j] = er*sn_;          // lambda
    float wr = lr[j]-1.0f, wi = li[j];
    float inv = 1.0f/(Are*Are + Aim*Aim);
    float qr = (wr*Are + wi*Aim)*inv;
    float qi = (wi*Are - wr*Aim)*inv;
    float Cr = C_re[hn], Ci = C_im[hn];
    dcr[j] = Cr*qr - Ci*qi;
    dci[j] = Cr*qi + Ci*qr;
    sr[j] = 0.f; si[j] = 0.f;
  }

  __shared__ float us[CHUNK][16];
  __shared__ float yps[CHUNK][16];
  const float* ubase = u + ((size_t)b*SEQL + k*CHUNK)*DIMH + hgb*16;
  for (int idx=lane; idx<CHUNK*16; idx+=64) {
    int t = idx>>4, c = idx&15;
    us[t][c] = ubase[(size_t)t*DIMH + c];
  }
  __syncthreads();

  for (int t=0; t<CHUNK; ++t) {
    float uv = us[t][ch];
    float lsum = 0.f;
#pragma unroll
    for (int j=0;j<8;j++) {
      float nsr = fmaf(lr[j], sr[j], fmaf(-li[j], si[j], uv));
      float nsi = fmaf(li[j], sr[j], lr[j]*si[j]);
      sr[j]=nsr; si[j]=nsi;
      lsum = fmaf(dcr[j], sr[j], fmaf(-dci[j], si[j], lsum));
    }
    lsum += __shfl_xor(lsum, 1);
    lsum += __shfl_xor(lsum, 2);
    if (slot==0) yps[t][ch] = 2.0f*lsum + uv*Dv;
  }
  __syncthreads();

  float* ybase = ypart + ((size_t)b*SEQL + k*CHUNK)*DIMH + hgb*16;
  for (int idx=lane; idx<CHUNK*16; idx+=64) {
    int t = idx>>4, c = idx&15;
    ybase[(size_t)t*DIMH + c] = yps[t][c];
  }
  float2* sb = (float2*)send + (((size_t)b*NCHUNK + k)*DIMH + h)*32 + slot*8;
#pragma unroll
  for (int j=0;j<8;j++) { float2 v; v.x=sr[j]; v.y=si[j]; sb[j]=v; }
}

__global__ __launch_bounds__(64) void s4_fix_kernel(
    const float* __restrict__ ypart, const float* __restrict__ send,
    const float* __restrict__ log_dt,
    const float* __restrict__ A_re, const float* __restrict__ A_im,
    const float* __restrict__ C_re, const float* __restrict__ C_im,
    __bf16* __restrict__ yout) {
  int bid = blockIdx.x;
  int k   = bid & (NCHUNK-1);
  int hgb = (bid >> 3) & 63;
  int b   = bid >> 9;
  int lane = threadIdx.x;
  int ch = lane >> 2, slot = lane & 3;
  int h = hgb*16 + ch;

  float dt = __expf(log_dt[h]);
  float lr[8], li[8], dcr[8], dci[8], Lr[8], Li[8];
#pragma unroll
  for (int j=0;j<8;j++) {
    int hn = h*32 + slot*8 + j;
    float Are = A_re[hn], Aim = A_im[hn];
    float ar = dt*Are, ai = dt*Aim;
    float er = __expf(ar);
    float sn_, cs_; __sincosf(ai, &sn_, &cs_);
    lr[j] = er*cs_; li[j] = er*sn_;              // lambda
    float eR = __expf((float)CHUNK*ar);          // lambda^CHUNK (direct)
    float sN, cN; __sincosf((float)CHUNK*ai, &sN, &cN);
    Lr[j] = eR*cN; Li[j] = eR*sN;
    float wr = lr[j]-1.0f, wi = li[j];
    float inv = 1.0f/(Are*Are + Aim*Aim);
    float qr = (wr*Are + wi*Aim)*inv;
    float qi = (wi*Are - wr*Aim)*inv;
    float Cr = C_re[hn], Ci = C_im[hn];
    dcr[j] = Cr*qr - Ci*qi;
    dci[j] = Cr*qi + Ci*qr;
  }

  // carry_in = sum_{j<k} Lambda^{k-1-j} * S_j  (Horner)
  float cr[8], ci[8];
#pragma unroll
  for (int j=0;j<8;j++){ cr[j]=0.f; ci[j]=0.f; }
  for (int j=0;j<k;j++) {
    const float2* sb = (const float2*)send + (((size_t)b*NCHUNK + j)*DIMH + h)*32 + slot*8;
#pragma unroll
    for (int jj=0;jj<8;jj++) {
      float2 s2 = sb[jj];
      float tr = fmaf(Lr[jj], cr[jj], fmaf(-Li[jj], ci[jj], s2.x));
      float ti = fmaf(Lr[jj], ci[jj], fmaf( Li[jj], cr[jj], s2.y));
      cr[jj]=tr; ci[jj]=ti;
    }
  }
  // w = lambda * carry (correction factor for t=0 is lambda^1)
  float wr[8], wi[8];
#pragma unroll
  for (int j=0;j<8;j++) {
    wr[j] = lr[j]*cr[j] - li[j]*ci[j];
    wi[j] = lr[j]*ci[j] + li[j]*cr[j];
  }

  __shared__ float yps[CHUNK][16];
  __shared__ __bf16 ybs[CHUNK][16];
  const float* ybase = ypart + ((size_t)b*SEQL + k*CHUNK)*DIMH + hgb*16;
  for (int idx=lane; idx<CHUNK*16; idx+=64) {
    int t = idx>>4, c = idx&15;
    yps[t][c] = ybase[(size_t)t*DIMH + c];
  }
  __syncthreads();

  for (int t=0; t<CHUNK; ++t) {
    float csum = 0.f;
#pragma unroll
    for (int j=0;j<8;j++)
      csum = fmaf(dcr[j], wr[j], fmaf(-dci[j], wi[j], csum));
#pragma unroll
    for (int j=0;j<8;j++) {
      float nwr = fmaf(lr[j], wr[j], -li[j]*wi[j]);
      float nwi = fmaf(lr[j], wi[j],  li[j]*wr[j]);
      wr[j]=nwr; wi[j]=nwi;
    }
    csum += __shfl_xor(csum, 1);
    csum += __shfl_xor(csum, 2);
    float yv = yps[t][ch] + 2.0f*csum;
    float t2 = 0.7978845608028654f*(yv + 0.044715f*yv*yv*yv);
    t2 = fminf(t2, 15.0f);
    float e = __expf(2.0f*t2);
    float th = (e-1.0f)/(e+1.0f);
    if (slot==0) ybs[t][ch] = (__bf16)(0.5f*yv*(1.0f+th));
  }
  __syncthreads();

  __bf16* obase = yout + ((size_t)b*SEQL + k*CHUNK)*DIMH + hgb*16;
  for (int idx=lane; idx<CHUNK*16; idx+=64) {
    int t = idx>>4, c = idx&15;
    obase[(size_t)t*DIMH + c] = ybs[t][c];
  }
}

// ============================ LDS-staged GEMM ============================
// C = act(A @ W^T + bias).  128x128 tile, BK=32, double-buffered.
// LDS tile [128 rows][4 chunks of 16B], chunk-XOR swizzle: stored chunk
// (row, c) holds logical chunk c ^ ((row>>1)&3) -> fixed-quad reads across
// 16 rows spread over all 8 bank-slots (2-way = free) instead of 8-way.
// A swizzled via pre-swizzled per-lane GLOBAL source (global_load_lds dest
// must stay linear); W swizzled at the ds_write address; reads apply the
// same XOR (involution).
// ACT: 0 = none (+bias,+resid), 1 = GLU sigmoid, 2 = GLU silu.

__device__ __forceinline__ void gload_lds16(const void* g, void* l) {
  __builtin_amdgcn_global_load_lds(
      (const __attribute__((address_space(1))) void*)g,
      (__attribute__((address_space(3))) void*)l, 16, 0, 0);
}

template<int ACT>
__global__ __launch_bounds__(256) void gemm_kernel(
    const __bf16* __restrict__ A, const float* __restrict__ W,
    const float* __restrict__ bias, const float* __restrict__ resid,
    float* __restrict__ outf, __bf16* __restrict__ outb,
    int Nout, int K) {
  constexpr int TILE = 128*32;                       // elems per buffer
  __shared__ __align__(16) __bf16 smem[(ACT ? 6 : 4) * TILE];
  __bf16* As = smem;                                  // [2][TILE]
  __bf16* Wa = smem + 2*TILE;                         // [2][TILE]
  __bf16* Wg = ACT ? (smem + 4*TILE) : nullptr;       // [2][TILE]

  int tid = threadIdx.x;
  int wave = tid>>6, lane = tid&63;
  int quad = lane>>4, l16 = lane&15;
  int m0 = blockIdx.x*128;
  int n0 = blockIdx.y*128;
  int wm = wave>>1, wn = wave&1;                      // 2x2 waves -> 64x64 each

  f32x4 acc[4][4];
  f32x4 accg[4][4];
  f32x4 zero = {0.f,0.f,0.f,0.f};
#pragma unroll
  for (int i=0;i<4;i++)
#pragma unroll
    for (int j=0;j<4;j++){ acc[i][j]=zero; if (ACT) accg[i][j]=zero; }

  size_t goff = (size_t)Nout*K;

  auto stage = [&](int buf, int k0) {
    // --- W f32 loads first ---
    f32x4 wlo[2], whi[2], glo[2], ghi[2];
#pragma unroll
    for (int c=0;c<2;c++) {
      int idx = c*256 + tid;                 // 0..511
      int rr = idx>>2, kq = (idx&3)*8;       // row 0..127, k 0/8/16/24
      const float* p = W + (size_t)(n0+rr)*K + k0 + kq;
      wlo[c] = *(const f32x4*)p; whi[c] = *(const f32x4*)(p+4);
      if (ACT) {
        const float* pg = p + goff;
        glo[c] = *(const f32x4*)pg; ghi[c] = *(const f32x4*)(pg+4);
      }
    }
    // --- A: async global->LDS, linear LDS dest, chunk-swizzled global src ---
#pragma unroll
    for (int q=0;q<2;q++) {
      int off = ((wave*2+q)*64 + lane)*16;   // per-lane byte offset in tile
      int row = off>>6;                      // row-major [128][64B]
      int cch = (off>>4)&3;
      int csrc = cch ^ ((row>>1)&3);         // pre-swizzle source chunk
      const char* src = (const char*)A + ((size_t)(m0+row)*K + k0)*2 + csrc*16;
      char* dst = (char*)As + (size_t)buf*TILE*2 + (size_t)(wave*2+q)*1024;
      gload_lds16(src, dst);
    }
    // --- W: cvt + swizzled ds_write_b128 ---
#pragma unroll
    for (int c=0;c<2;c++) {
      int idx = c*256 + tid;
      int rr = idx>>2, cc = idx&3;
      int cs = cc ^ ((rr>>1)&3);
      bf16x8 t;
      t[0]=(__bf16)wlo[c].x; t[1]=(__bf16)wlo[c].y; t[2]=(__bf16)wlo[c].z; t[3]=(__bf16)wlo[c].w;
      t[4]=(__bf16)whi[c].x; t[5]=(__bf16)whi[c].y; t[6]=(__bf16)whi[c].z; t[7]=(__bf16)whi[c].w;
      *(bf16x8*)(Wa + buf*TILE + rr*32 + cs*8) = t;
      if (ACT) {
        bf16x8 t2;
        t2[0]=(__bf16)glo[c].x; t2[1]=(__bf16)glo[c].y; t2[2]=(__bf16)glo[c].z; t2[3]=(__bf16)glo[c].w;
        t2[4]=(__bf16)ghi[c].x; t2[5]=(__bf16)ghi[c].y; t2[6]=(__bf16)ghi[c].z; t2[7]=(__bf16)ghi[c].w;
        *(bf16x8*)(Wg + buf*TILE + rr*32 + cs*8) = t2;
      }
    }
  };

  stage(0, 0);
  __syncthreads();

  int nt = K/32;
  for (int t=0; t<nt; ++t) {
    int cur = t&1, nxt = cur^1;
    if (t+1 < nt) stage(nxt, (t+1)*32);       // prefetch next tile
    int base = cur*TILE;
    bf16x8 af[4], wf[4], wgf[4];
#pragma unroll
    for (int i=0;i<4;i++) {
      int ra = wm*64 + i*16 + l16;
      af[i] = *(const bf16x8*)(As + base + ra*32 + (quad ^ ((ra>>1)&3))*8);
    }
#pragma unroll
    for (int j=0;j<4;j++) {
      int rb = wn*64 + j*16 + l16;
      int cs = (quad ^ ((rb>>1)&3))*8;
      wf[j] = *(const bf16x8*)(Wa + base + rb*32 + cs);
      if (ACT) wgf[j] = *(const bf16x8*)(Wg + base + rb*32 + cs);
    }
#pragma unroll
    for (int i=0;i<4;i++)
#pragma unroll
      for (int j=0;j<4;j++) {
        acc[i][j] = __builtin_amdgcn_mfma_f32_16x16x32_bf16(af[i], wf[j], acc[i][j], 0,0,0);
        if (ACT)
          accg[i][j] = __builtin_amdgcn_mfma_f32_16x16x32_bf16(af[i], wgf[j], accg[i][j], 0,0,0);
      }
    __syncthreads();
  }

  // epilogue — C/D layout: col = lane&15, row = quad*4 + reg
#pragma unroll
  for (int i=0;i<4;i++) {
#pragma unroll
    for (int j=0;j<4;j++) {
      int colg = n0 + wn*64 + j*16 + l16;
      float ba = bias[colg];
      float bg = ACT ? bias[Nout + colg] : 0.f;
#pragma unroll
      for (int rr=0;rr<4;rr++) {
        int rowg = m0 + wm*64 + i*16 + quad*4 + rr;
        float v = acc[i][j][rr] + ba;
        if (ACT) {
          float g = accg[i][j][rr] + bg;
          float sg = 1.0f/(1.0f+__expf(-g));
          v = (ACT==1) ? v*sg : v*(g*sg);
        }
        size_t idx = (size_t)rowg*Nout + colg;
        if (resid) v += resid[idx];
        if (outf) outf[idx] = v;
        if (outb) outb[idx] = (__bf16)v;
      }
    }
  }
}

// ============================ host ============================
static void launch_gemm(int act, const __bf16* A, const float* W, const float* bias,
                        const float* resid, float* outf, __bf16* outb,
                        int Nout, int K, hipStream_t s) {
  dim3 g(NROWS/128, Nout/128), b(256);       // M fastest -> W-tile L2 reuse
  if (act==0)      gemm_kernel<0><<<g,b,0,s>>>(A,W,bias,resid,outf,outb,Nout,K);
  else if (act==1) gemm_kernel<1><<<g,b,0,s>>>(A,W,bias,resid,outf,outb,Nout,K);
  else             gemm_kernel<2><<<g,b,0,s>>>(A,W,bias,resid,outf,outb,Nout,K);
}

extern "C" void kernel_launch(void* const* d_in, const int* in_sizes, int n_in,
                              void* d_out, int out_size, void* d_ws, size_t ws_size,
                              hipStream_t stream) {
  (void)in_sizes; (void)n_in; (void)out_size; (void)ws_size;
  const int*   x        = (const int*)d_in[0];
  // d_in[1] = length (unused by reference)
  const float* emb      = (const float*)d_in[2];
  const float* s4_log_dt= (const float*)d_in[3];
  const float* s4_A_re  = (const float*)d_in[4];
  const float* s4_A_im  = (const float*)d_in[5];
  const float* s4_C_re  = (const float*)d_in[6];
  const float* s4_C_im  = (const float*)d_in[7];
  const float* s4_D     = (const float*)d_in[8];
  const float* s4_out_w = (const float*)d_in[9];
  const float* s4_out_b = (const float*)d_in[10];
  const float* norm1_w  = (const float*)d_in[11];
  const float* norm1_b  = (const float*)d_in[12];
  const float* norm2_w  = (const float*)d_in[13];
  const float* norm2_b  = (const float*)d_in[14];
  const float* ff_w1    = (const float*)d_in[15];
  const float* ff_b1    = (const float*)d_in[16];
  const float* ff_w2    = (const float*)d_in[17];
  const float* ff_b2    = (const float*)d_in[18];
  const float* post_w   = (const float*)d_in[19];
  const float* post_b   = (const float*)d_in[20];
  const float* out_w    = (const float*)d_in[21];
  const float* out_b    = (const float*)d_in[22];

  char* ws = (char*)d_ws;
  float*  h    = (float*)(ws + 0);                    // 16 MB  [4096,1024] f32
  float*  r    = (float*)(ws + (16u<<20));            // 16 MB  [4096,1024] f32
  __bf16* yb   = (__bf16*)(ws + (32u<<20));           //  8 MB  [4096,1024] bf16
  __bf16* lnb  = (__bf16*)(ws + (40u<<20));           //  8 MB  bf16 (LN out) / scan send scratch
  __bf16* glub = (__bf16*)(ws + (48u<<20));           // 32 MB  bf16 (GLU out) / scan ypart scratch
  float*  sendF  = (float*)(ws + (40u<<20));          //  8 MB  [4,8,1024,32] float2 (= lnb region)
  float*  ypartF = (float*)(ws + (48u<<20));          // 16 MB  [4096,1024] f32 (= glub region)
  float*  logits = (float*)d_out;                     // [4096,32000] f32

  embed_kernel<<<NROWS,256,0,stream>>>(x, emb, h);

  for (int i=0;i<4;i++) {
    // ---- S4 block: r = LN1(h); r = S4(S4(r)); h = r + h ----
    ln_kernel<<<NROWS,256,0,stream>>>(h, norm1_w+(size_t)i*DIMH, norm1_b+(size_t)i*DIMH, r, nullptr);
    for (int j=0;j<2;j++) {
      int k = 2*i+j;
      s4_chunk_kernel<<<BATCHN*64*NCHUNK,64,0,stream>>>(r, s4_log_dt + (size_t)k*DIMH,
          s4_A_re + (size_t)k*DIMH*32, s4_A_im + (size_t)k*DIMH*32,
          s4_C_re + (size_t)k*DIMH*32, s4_C_im + (size_t)k*DIMH*32,
          s4_D + (size_t)k*DIMH, ypartF, sendF);
      s4_fix_kernel<<<BATCHN*64*NCHUNK,64,0,stream>>>(ypartF, sendF,
          s4_log_dt + (size_t)k*DIMH,
          s4_A_re + (size_t)k*DIMH*32, s4_A_im + (size_t)k*DIMH*32,
          s4_C_re + (size_t)k*DIMH*32, s4_C_im + (size_t)k*DIMH*32, yb);
      const float* sw    = s4_out_w + (size_t)k*2048*DIMH;
      const float* sbias = s4_out_b + (size_t)k*2048;
      if (j==0)  // r = a*sigmoid(g)
        launch_gemm(1, yb, sw, sbias, nullptr, r, nullptr, DIMH, DIMH, stream);
      else       // h = a*sigmoid(g) + h
        launch_gemm(1, yb, sw, sbias, h, h, nullptr, DIMH, DIMH, stream);
    }
    // ---- FFN block: r = LN2(h); h = (a*silu(g)) @ w2^T + b2 + h ----
    ln_kernel<<<NROWS,256,0,stream>>>(h, norm2_w+(size_t)i*DIMH, norm2_b+(size_t)i*DIMH, r, lnb);
    launch_gemm(2, lnb, ff_w1 + (size_t)i*8192*DIMH, ff_b1 + (size_t)i*8192,
                nullptr, nullptr, glub, 4096, DIMH, stream);
    launch_gemm(0, glub, ff_w2 + (size_t)i*DIMH*4096, ff_b2 + (size_t)i*DIMH,
                h, h, nullptr, DIMH, 4096, stream);
  }

  // ---- post-norm + logits ----
  ln_kernel<<<NROWS,256,0,stream>>>(h, post_w, post_b, r, lnb);
  launch_gemm(0, lnb, out_w, out_b, nullptr, logits, nullptr, 32000, DIMH, stream);
}